// Round 5
// baseline (303.268 us; speedup 1.0000x reference)
//
#include <hip/hip_runtime.h>
#include <hip/hip_bf16.h>

// Problem constants (from reference): B=512, T=64, A=32, H=512, E=32
#define B_ 512
#define T_ 64
#define A_ 32
#define H_ 512
#define E_ 32
#define MAX_TASKS 272   // sum_e ceil(cnt_e/2) <= 256 + 16
#define CAP_ 168        // itemlist capacity per XCD class
#define GRID_ (8 * CAP_)
#define TSC 16          // tau-bias samples per chunk

typedef unsigned short u16;
typedef unsigned int u32;
typedef __attribute__((ext_vector_type(8))) short short8;   // 8 bf16 (MFMA A/B frag)
typedef __attribute__((ext_vector_type(4))) float floatx4;  // MFMA C/D frag

static __device__ __forceinline__ u16 f2bf(float f) {
    u32 u = __builtin_bit_cast(u32, f);
    u += 0x7fffu + ((u >> 16) & 1u);   // RNE
    return (u16)(u >> 16);
}

// async global->LDS, 16B per lane; LDS dest is wave-uniform base (HW adds
// lane*16). Swizzle must be applied on the GLOBAL address per lane.
static __device__ __forceinline__ void gl2lds16(const u16* g, u16* l) {
    __builtin_amdgcn_global_load_lds(
        (const __attribute__((address_space(1))) void*)g,
        (__attribute__((address_space(3))) void*)l, 16, 0, 0);
}

// ---------------------------------------------------------------------------
// Launch 1 (FUSED): blocks [0,512) = per-sample embed work; block 512 = the
// grouping block. Embed: GEMM1 (K=32, fp32 VALU, 1 col/thread) -> bf16
// a_emb; tau table tauG[s][512] (2 trig/thread); bias2s[s][:] = b2[e(s)][:].
// ---------------------------------------------------------------------------
__global__ __launch_bounds__(512) void embed_group_kernel(
        const float* __restrict__ actions, const float* __restrict__ timesteps,
        const int* __restrict__ cat_ids, const float* __restrict__ W1,
        const float* __restrict__ b1, const float* __restrict__ b2,
        u16* __restrict__ a_emb, float* __restrict__ tauG,
        float* __restrict__ bias2s,
        int* __restrict__ sample_list, int4* __restrict__ tasks,
        int* __restrict__ itemlist, int* __restrict__ eoff_g,
        int* __restrict__ ecnt_g) {
    int tid = threadIdx.x;

    if (blockIdx.x == B_) {
        // ------------------- grouping block (uniform branch) -------------------
        __shared__ int cnt[E_], off[E_], cur[E_], toff[E_], jc[8];
        __shared__ int total, fb;
        if (tid < E_) { cnt[tid] = 0; cur[tid] = 0; }
        __syncthreads();
        int e = cat_ids[tid];               // tid in [0,512) == B_
        atomicAdd(&cnt[e], 1);
        __syncthreads();
        if (tid == 0) {
            int run = 0, trun = 0;
            for (int i = 0; i < E_; i++) {
                off[i] = run;  run += cnt[i];
                toff[i] = trun; trun += (cnt[i] + 1) >> 1;
            }
            total = trun;
        }
        __syncthreads();
        if (tid < E_) {
            int c = cnt[tid], o = off[tid], to = toff[tid];
            eoff_g[tid] = o;
            ecnt_g[tid] = c;
            for (int j = 0; j < c; j += 2)
                tasks[to++] = make_int4(tid, o + j, (c - j >= 2) ? 2 : 1, 0);
        }
        if (tid < 8) {
            int J = 0;
            for (int cc = 0; cc < 4; cc++)
                J += 4 * ((cnt[tid + 8 * cc] + 1) >> 1);
            jc[tid] = J;
        }
        __syncthreads();
        if (tid == 0) {
            int f = 0;
            for (int x = 0; x < 8; x++) if (jc[x] > CAP_) f = 1;
            fb = f;
        }
        __syncthreads();
        if (!fb) {
            if (tid < 8) {
                int j = 0;
                for (int cc = 0; cc < 4; cc++) {
                    int ee = tid + 8 * cc;
                    int nt = (cnt[ee] + 1) >> 1, t0 = toff[ee];
                    for (int t = t0; t < t0 + nt; t++)
                        for (int nb = 0; nb < 4; nb++) {
                            itemlist[tid + 8 * j] = (t << 2) | nb;
                            j++;
                        }
                }
                for (; j < CAP_; j++) itemlist[tid + 8 * j] = -1;
            }
        } else {
            for (int f = tid; f < GRID_; f += 512)
                itemlist[f] = (f < 4 * total) ? f : -1;
        }
        int p = atomicAdd(&cur[e], 1);
        sample_list[off[e] + p] = tid;
        return;
    }

    // ---------------------------- embed block ----------------------------
    int b = blockIdx.x;
    int e = cat_ids[b];
    {
        float tval = timesteps[b];
        int kk = tid & 255;
        float freq = expf(-9.210340371976184f * (float)kk * (1.0f / 256.0f));
        float ang = tval * freq;
        tauG[(size_t)b * H_ + tid] = (tid < 256) ? sinf(ang) : cosf(ang);
        bias2s[(size_t)b * H_ + tid] = b2[e * H_ + tid];
    }

    __shared__ float act[T_ * A_];
    const float* asrc = actions + (size_t)b * T_ * A_;
    for (int i = tid; i < T_ * A_; i += 512) act[i] = asrc[i];
    __syncthreads();

    const float* w1 = W1 + (size_t)e * A_ * H_;
    float wcol[A_];
#pragma unroll
    for (int k = 0; k < A_; k++) wcol[k] = w1[k * H_ + tid];
    float bb = b1[e * H_ + tid];
    u16* orow = a_emb + (size_t)b * T_ * H_;
    for (int tt = 0; tt < T_; tt++) {
        float acc = bb;
#pragma unroll
        for (int k = 0; k < A_; k++)
            acc = fmaf(act[tt * A_ + k], wcol[k], acc);   // LDS broadcast
        orow[tt * H_ + tid] = f2bf(acc);
    }
}

// ---------------------------------------------------------------------------
// convert-transpose core: W [e][srcK][512] f32 rows [k0,k0+64) ->
// Wt [e][512][dstK] bf16. Each thread writes a full 128B contiguous run of
// its Wt row (whole L2 lines covered by one thread).
// ---------------------------------------------------------------------------
static __device__ __forceinline__ void ct_block(
        const float* __restrict__ W, u16* __restrict__ Wt,
        int srcK, int dstK, int e, int k0, int n) {
    const float* src = W + ((size_t)e * srcK + k0) * H_ + n;
    short8 out[8];
#pragma unroll
    for (int j = 0; j < 64; j++)
        out[j >> 3][j & 7] = (short)f2bf(src[(size_t)j * H_]);
    u16* dst = Wt + ((size_t)e * H_ + n) * dstK + k0;
#pragma unroll
    for (int c = 0; c < 8; c++) *(short8*)(dst + c * 8) = out[c];
}

// ---------------------------------------------------------------------------
// Kernel: standalone ct (used for W3 after GEMM2 frees the a_emb buffer).
// grid (dstK/64, 2, E_)
// ---------------------------------------------------------------------------
__global__ __launch_bounds__(256) void convert_transpose(
        const float* __restrict__ W, u16* __restrict__ Wt, int srcK, int dstK) {
    ct_block(W, Wt, srcK, dstK, blockIdx.z, blockIdx.x * 64,
             blockIdx.y * 256 + threadIdx.x);
}

// ---------------------------------------------------------------------------
// Launch 2 (FUSED): blocks [0,512) = ct of W2 rows [0,512) -> Wt2a;
// blocks [512,1024) = tau_bias: bias2s[s][n] += tauG_f32[s] . W2b_f32[e].
//
// Round-4 post-mortem: old tau half was STILL latency-bound (VALU 9.7%,
// HBM 17%, 47 us): scalar 4B W loads, cross-wave k-split reduce with 3
// barriers/chunk, 8-way-conflicted tauT writes.
// NEW tau structure:
//  - block = (e, 64-k slice ks, 256-n half nh): 32*8*2 = 512 blocks
//    (+512 ct = 4 blocks/CU TLP).
//  - waves split SAMPLES (4 each of the 16-chunk), not k -> no cross-wave
//    reduce, ONE barrier per chunk.
//  - float4 W loads (16B/lane, coalescing sweet spot), unroll 8 -> 8 in
//    flight/thread; 16 FMA per load.
//  - tauT[64][17]: stride 17 coprime 32 -> conflict-free writes; reads are
//    wave-broadcast (conflict-free by definition).
//  - per-thread acc[4s][4n] in regs; epilogue = 16 unsafeAtomicAdd (f32 hw
//    atomics, ~2.1M total, ~8MB traffic - negligible).
// W2 read exactly once chip-wide across the two halves.
// ---------------------------------------------------------------------------
__global__ __launch_bounds__(256) void prep_kernel(
        const float* __restrict__ W2, u16* __restrict__ Wt2a,
        const float* __restrict__ tauG, const int* __restrict__ sample_list,
        const int* __restrict__ eoff, const int* __restrict__ ecnt,
        float* __restrict__ bias2s) {
    int tid = threadIdx.x;
    int bid = blockIdx.x;

    if (bid < 512) {
        int e = bid >> 4, sub = bid & 15;
        ct_block(W2, Wt2a, 2 * H_, H_, e, (sub & 7) * 64,
                 (sub >> 3) * 256 + tid);
        return;
    }

    __shared__ float tauT[64][17];     // [k][sl]; stride 17 -> conflict-free
    int id = bid - 512;
    int nh = id & 1;                   // 0..1: 256-col half
    int ks = (id >> 1) & 7;            // 0..7: 64-k slice
    int e  = id >> 4;
    int cnt = ecnt[e], off = eoff[e];
    if (cnt == 0) return;
    int wv = tid >> 6, ln = tid & 63;
    const float* wb = W2 + ((size_t)e * 1024 + 512 + ks * 64) * H_
                      + nh * 256 + ln * 4;            // [k][n], f32x4/lane
    float* bout = bias2s + nh * 256 + ln * 4;

    for (int c0 = 0; c0 < cnt; c0 += TSC) {
        // stage tau slice transposed: tauT[k][sl] = tauG[s(sl)][ks*64+k]
        for (int i = tid; i < TSC * 64; i += 256) {
            int sl = i >> 6, k = i & 63;
            float v = 0.f;
            if (c0 + sl < cnt)
                v = tauG[(size_t)sample_list[off + c0 + sl] * H_ + ks * 64 + k];
            tauT[k][sl] = v;
        }
        __syncthreads();

        float4 a0 = {0,0,0,0}, a1 = {0,0,0,0}, a2 = {0,0,0,0}, a3 = {0,0,0,0};
#pragma unroll 8
        for (int k = 0; k < 64; k++) {
            float4 w4 = *(const float4*)(wb + (size_t)k * H_);  // 1KB/wave
            float t0 = tauT[k][wv * 4 + 0];     // LDS broadcast
            float t1 = tauT[k][wv * 4 + 1];
            float t2 = tauT[k][wv * 4 + 2];
            float t3 = tauT[k][wv * 4 + 3];
            a0.x = fmaf(t0, w4.x, a0.x); a0.y = fmaf(t0, w4.y, a0.y);
            a0.z = fmaf(t0, w4.z, a0.z); a0.w = fmaf(t0, w4.w, a0.w);
            a1.x = fmaf(t1, w4.x, a1.x); a1.y = fmaf(t1, w4.y, a1.y);
            a1.z = fmaf(t1, w4.z, a1.z); a1.w = fmaf(t1, w4.w, a1.w);
            a2.x = fmaf(t2, w4.x, a2.x); a2.y = fmaf(t2, w4.y, a2.y);
            a2.z = fmaf(t2, w4.z, a2.z); a2.w = fmaf(t2, w4.w, a2.w);
            a3.x = fmaf(t3, w4.x, a3.x); a3.y = fmaf(t3, w4.y, a3.y);
            a3.z = fmaf(t3, w4.z, a3.z); a3.w = fmaf(t3, w4.w, a3.w);
        }

#pragma unroll
        for (int si = 0; si < 4; si++) {
            int sl = wv * 4 + si;
            if (c0 + sl < cnt) {
                int s = sample_list[off + c0 + sl];
                float4 a = (si == 0) ? a0 : (si == 1) ? a1 : (si == 2) ? a2 : a3;
                float* p = bout + (size_t)s * H_;
                unsafeAtomicAdd(p + 0, a.x);
                unsafeAtomicAdd(p + 1, a.y);
                unsafeAtomicAdd(p + 2, a.z);
                unsafeAtomicAdd(p + 3, a.w);
            }
        }
        __syncthreads();
    }
}

// ---------------------------------------------------------------------------
// Kernels GEMM2/GEMM3: expert-grouped MFMA GEMM, K=512 (tau folded out).
// Block: 256 threads (4 waves), tile M=128 (2 samples) x N=128, BK=64.
// True 2-deep pipeline (T3+T4): raw s_barrier + counted vmcnt(8).
// Per iter: compute(t) -> s_barrier (all waves done reading buf[t&1]) ->
// stage(t+2) into buf[t&1] -> s_waitcnt vmcnt(8) (waits ONLY t+1's 8 loads;
// t+2's 8 stay in flight across the barrier) -> s_barrier -> next iter.
// Swizzle: 16B chunk c of row r at slot c^(r&7), applied on the global
// address side (gl2lds dest must be linear); frag reads conflict-free.
// ---------------------------------------------------------------------------
template <int DIN, bool PSBIAS, bool DO_SWISH, bool OUT_BF16>
__global__ __launch_bounds__(256, 2) void moe_gemm(
        const u16* __restrict__ xsrc, const u16* __restrict__ Wt,
        const float* __restrict__ bias,
        const int* __restrict__ sample_list, const int4* __restrict__ tasks,
        const int* __restrict__ itemlist, void* __restrict__ outp) {
    int item = itemlist[blockIdx.x];
    if (item < 0) return;
    int4 task = tasks[item >> 2];
    int nb = item & 3;
    int ns = task.z;
    int e = task.x;
    int s0 = sample_list[task.y];
    int s1 = (ns > 1) ? sample_list[task.y + 1] : s0;  // dup reads, masked store
    int n0 = nb * 128;

    int tid = threadIdx.x;
    int lane = tid & 63, wv = tid >> 6;          // 4 waves
    int wr = wv >> 1, wc = wv & 1;               // 2x2 wave grid
    int quad = lane >> 4, c15 = lane & 15;
    int r8 = lane >> 3, cg = lane & 7;           // staging: row-in-group, chunk

    __shared__ __align__(16) u16 xs[2][128 * 64];   // 2 x 16 KB
    __shared__ __align__(16) u16 wt[2][128 * 64];   // 2 x 16 KB

    floatx4 acc[4][4];
    floatx4 zero4 = {0.f, 0.f, 0.f, 0.f};
#pragma unroll
    for (int i = 0; i < 4; i++)
#pragma unroll
        for (int j = 0; j < 4; j++) acc[i][j] = zero4;

    const u16* wbase = Wt + (size_t)(e * H_ + n0) * DIN;
    int kc_sw = (cg ^ r8) * 8;                   // swizzled global k-offset

    auto stage = [&](int b, int k0) {            // 8 loads per wave
#pragma unroll
        for (int h = 0; h < 4; h++) {
            int rbase = h * 32 + wv * 8;         // wave-uniform row-group base
            int s = (h < 2) ? s0 : s1;
            int t = (rbase + r8) & 63;
            gl2lds16(xsrc + ((size_t)s * T_ + t) * H_ + k0 + kc_sw,
                     &xs[b][rbase * 64]);
        }
#pragma unroll
        for (int h = 0; h < 4; h++) {
            int nbase = h * 32 + wv * 8;
            gl2lds16(wbase + (size_t)(nbase + r8) * DIN + k0 + kc_sw,
                     &wt[b][nbase * 64]);
        }
    };

    auto compute = [&](int b) {
#pragma unroll
        for (int kk = 0; kk < 2; kk++) {
            int c = kk * 4 + quad;               // k-chunk index 0..7
            short8 af[4], bfr[4];
#pragma unroll
            for (int i = 0; i < 4; i++) {
                int row = wr * 64 + i * 16 + c15;
                af[i] = *(const short8*)&xs[b][row * 64 + ((c ^ (row & 7)) * 8)];
                int nr = wc * 64 + i * 16 + c15;
                bfr[i] = *(const short8*)&wt[b][nr * 64 + ((c ^ (nr & 7)) * 8)];
            }
#pragma unroll
            for (int mt = 0; mt < 4; mt++)
#pragma unroll
                for (int nt = 0; nt < 4; nt++)
                    acc[mt][nt] = __builtin_amdgcn_mfma_f32_16x16x32_bf16(
                            af[mt], bfr[nt], acc[mt][nt], 0, 0, 0);
        }
    };

    constexpr int KI = DIN / 64;                 // 8 K-iterations
    stage(0, 0);                                 // 8 loads (buf0)
    stage(1, 64);                                // 8 loads (buf1)
    asm volatile("s_waitcnt vmcnt(8)" ::: "memory");  // own buf0 loads done
    __builtin_amdgcn_s_barrier();                // all waves' buf0 done
    __builtin_amdgcn_sched_barrier(0);
#pragma unroll
    for (int t = 0; t < KI; ++t) {
        compute(t & 1);
        if (t + 1 < KI) {
            __builtin_amdgcn_s_barrier();        // all waves done reading buf[t&1]
            __builtin_amdgcn_sched_barrier(0);
            if (t + 2 < KI) {
                stage(t & 1, (t + 2) * 64);      // buf[(t+2)&1] == buf[t&1]
                asm volatile("s_waitcnt vmcnt(8)" ::: "memory"); // t+1 done
            } else {
                asm volatile("s_waitcnt vmcnt(0)" ::: "memory"); // drain last
            }
            __builtin_amdgcn_s_barrier();        // all waves' t+1 loads done
            __builtin_amdgcn_sched_barrier(0);
        }
    }

    // ---- epilogue: C/D layout col=c15, row=quad*4+r; wave-row wr = sample ----
    if (wr >= ns) return;
    int s = (wr == 0) ? s0 : s1;
    const float* bp = PSBIAS ? (bias + (size_t)s * H_)   // per-sample (GEMM2)
                             : (bias + (size_t)e * H_);  // per-expert (GEMM3)
#pragma unroll
    for (int mt = 0; mt < 4; mt++) {
        int tb = mt * 16 + quad * 4;             // t base within sample
#pragma unroll
        for (int nt = 0; nt < 4; nt++) {
            int col = n0 + wc * 64 + nt * 16 + c15;
            float bv = bp[col];
#pragma unroll
            for (int r = 0; r < 4; r++) {
                float v = acc[mt][nt][r] + bv;
                if (DO_SWISH) v = v / (1.0f + expf(-v));   // x*sigmoid(x)
                size_t oidx = ((size_t)s * T_ + tb + r) * H_ + col;
                if (OUT_BF16) ((u16*)outp)[oidx] = f2bf(v);
                else          ((float*)outp)[oidx] = v;
            }
        }
    }
}

// ---------------------------------------------------------------------------
extern "C" void kernel_launch(void* const* d_in, const int* in_sizes, int n_in,
                              void* d_out, int out_size, void* d_ws, size_t ws_size,
                              hipStream_t stream) {
    const float* actions   = (const float*)d_in[0];
    const float* timesteps = (const float*)d_in[1];
    const int*   cat_ids   = (const int*)d_in[2];
    const float* W1 = (const float*)d_in[3];
    const float* b1 = (const float*)d_in[4];
    const float* W2 = (const float*)d_in[5];
    const float* b2 = (const float*)d_in[6];
    const float* W3 = (const float*)d_in[7];
    const float* b3 = (const float*)d_in[8];

    // ws: a_emb 32MB (reused as Wt3 after GEMM2) | y 32MB | meta.
    // d_out (64 MiB) is scratch until GEMM3's epilogue:
    //   Wt2a bf16 16MiB @0 | bias2s f32 1MiB @48MiB | tauG f32 1MiB @52MiB.
    char* ws = (char*)d_ws;
    u16* a_emb = (u16*)ws;
    u16* y     = (u16*)(ws + (size_t)32 * 1024 * 1024);
    char* meta = ws + (size_t)64 * 1024 * 1024 + 512 * 1024;
    int*  sample_list = (int*)meta;                     // 2 KB
    int4* tasks       = (int4*)(meta + 8192);           // 272*16 B
    int*  itemlist    = (int*)(meta + 16384);           // GRID_*4 B
    int*  eoff        = (int*)(meta + 24576);           // 128 B
    int*  ecnt        = (int*)(meta + 24576 + 128);     // 128 B
    u16*  Wt2a   = (u16*)d_out;
    float* bias2s = (float*)((char*)d_out + (size_t)48 * 1024 * 1024);
    float* tauG   = (float*)((char*)d_out + (size_t)52 * 1024 * 1024);
    u16*  Wt3    = a_emb;

    // Launch 1: embed (512 blocks) + group (block 512)
    hipLaunchKernelGGL(embed_group_kernel, dim3(B_ + 1), dim3(512), 0, stream,
                       actions, timesteps, cat_ids, W1, b1, b2,
                       a_emb, tauG, bias2s,
                       sample_list, tasks, itemlist, eoff, ecnt);
    // Launch 2: ct2 (512 blocks) + tau_bias (512 blocks)
    hipLaunchKernelGGL(prep_kernel, dim3(1024), dim3(256), 0, stream,
                       W2, Wt2a, tauG, sample_list, eoff, ecnt, bias2s);
    // Launch 3: GEMM2
    hipLaunchKernelGGL((moe_gemm<H_, true, true, true>), dim3(GRID_),
                       dim3(256), 0, stream,
                       a_emb, Wt2a, bias2s, sample_list, tasks, itemlist,
                       (void*)y);
    // Launch 4: ct3 (a_emb buffer is dead now)
    hipLaunchKernelGGL(convert_transpose, dim3(H_ / 64, 2, E_), dim3(256),
                       0, stream, W3, Wt3, H_, H_);
    // Launch 5: GEMM3
    hipLaunchKernelGGL((moe_gemm<H_, false, false, false>), dim3(GRID_),
                       dim3(256), 0, stream,
                       y, Wt3, b3, sample_list, tasks, itemlist, d_out);
}